// Round 6
// baseline (46.654 us; speedup 1.0000x reference)
//
#include <hip/hip_runtime.h>

// Depth-4 path signature, N=64, L=512, C=8. Output/batch:
// [sig1(8) | sig2(64) | sig3(512) | sig4(4096)] = 4680 f32.
//
// SINGLE fused kernel (R3-R5 showed ~27us invariant to kernel rewrites =>
// two-dispatch fixed cost; remove it). Grid 256 blocks (= batch x l-quarter),
// 1024 threads = 16 waves:
//   Phase A: wave w scans chunk w (32 segs): full lvl1-3 scan + lvl4 acc
//            restricted to this block's l-pair (lq*2, lq*2+1). All in regs.
//            Chunk lvl1-3 -> LDS slot (lvl3 stride-65: 2-way banks max).
//   Phase B: each wave folds prefix A = chunk0 (x) ... (x) chunk_{w-1}
//            (levels 1-3 only, Chen) from LDS into registers.
//   Phase C: lvl4 contribution of chunk w to the final signature:
//            D4[ijkl] = B4 + A3[ijk]B1[l] + A2[ij]B2[kl] + A1[i]B3[jkl]
//            -> ds atomicAdd into shared 1024-float accumulator.
//   wave15/lq0: one more fold (chunk 15) = full lvl1-3 -> write out.
//   Tail: 512 threads copy summed lvl4 to out (float2, this block's l-pair).

static constexpr int L = 512;
static constexpr int NC = 8;
static constexpr int NSEG = L - 1;               // 511
static constexpr int SIG = 8 + 64 + 512 + 4096;  // 4680
static constexpr int SLOT = 592;                 // 8 lvl1 + 64 lvl2 + 520 lvl3(stride65)
static constexpr int L4OFF = 16 * SLOT;          // 9472
static constexpr int LDSF = L4OFF + 1024;        // 10496 floats = 42 KB

__device__ __forceinline__ float sel8(float d0, float d1, float d2, float d3,
                                      float d4, float d5, float d6, float d7,
                                      bool b0, bool b1, bool b2) {
    float x0 = b0 ? d1 : d0;
    float x1 = b0 ? d3 : d2;
    float x2 = b0 ? d5 : d4;
    float x3 = b0 ? d7 : d6;
    float y0 = b1 ? x1 : x0;
    float y1 = b1 ? x3 : x2;
    return b2 ? y1 : y0;
}

__global__ __launch_bounds__(1024, 4) void sig_fused(const float* __restrict__ path,
                                                     float* __restrict__ out) {
    __shared__ float lds[LDSF];
    const int tid = threadIdx.x;
    const int w = tid >> 6;        // wave = chunk 0..15
    const int lane = tid & 63;
    const int i = lane >> 3;
    const int j = lane & 7;
    const int n = blockIdx.x >> 2;   // batch
    const int lq = blockIdx.x & 3;   // l-quarter: l = lq*2, lq*2+1

    lds[L4OFF + tid] = 0.f;  // zero lvl4 accumulator (1024 floats)

    // ---------------- Phase A: chunk scan ----------------
    const int seg0 = w * 32;
    const int len = min(32, NSEG - seg0);
    const float* p = path + (size_t)n * (L * NC) + (size_t)seg0 * NC;

    const bool ib0 = lane & 8, ib1 = lane & 16, ib2 = lane & 32;
    const bool jb0 = lane & 1, jb1 = lane & 2, jb2 = lane & 4;
    const bool lb0 = lq & 1, lb1 = lq & 2;

    float s1 = 0.f, s2 = 0.f;
    float s3[8];
    float2 acc[8];
#pragma unroll
    for (int k = 0; k < 8; ++k) {
        s3[k] = 0.f;
        acc[k] = make_float2(0.f, 0.f);
    }
    constexpr float c3 = 1.f / 6.f;
    constexpr float c4 = 1.f / 24.f;

    float4 p0 = *reinterpret_cast<const float4*>(p);
    float4 p1 = *reinterpret_cast<const float4*>(p + 4);
#pragma unroll 2
    for (int s = 0; s < len; ++s) {
        const float4 q0 = *reinterpret_cast<const float4*>(p + (s + 1) * 8);
        const float4 q1 = *reinterpret_cast<const float4*>(p + (s + 1) * 8 + 4);
        const float d0 = q0.x - p0.x, d1 = q0.y - p0.y;
        const float d2 = q0.z - p0.z, d3 = q0.w - p0.w;
        const float d4 = q1.x - p1.x, d5 = q1.y - p1.y;
        const float d6 = q1.z - p1.z, d7 = q1.w - p1.w;
        p0 = q0;
        p1 = q1;

        const float di = sel8(d0, d1, d2, d3, d4, d5, d6, d7, ib0, ib1, ib2);
        const float dj = sel8(d0, d1, d2, d3, d4, d5, d6, d7, jb0, jb1, jb2);
        // this block's two l-increments (uniform selection by lq)
        const float ea = lb0 ? d2 : d0, eb = lb0 ? d6 : d4;
        const float dl0 = lb1 ? eb : ea;
        const float ec = lb0 ? d3 : d1, ed = lb0 ? d7 : d5;
        const float dl1 = lb1 ? ed : ec;

        const float u = fmaf(s1, c3, di * c4);    // s1/6 + di/24
        float vv = fmaf(s1, dj * 0.5f, s2);       // s2 + s1*dj/2
        vv = fmaf(di * dj, c3, vv);               // + di*dj/6
        const float w_ = fmaf(s2, 0.5f, dj * u);  // s2/2 + dj*u

#define KSTEP(kk, dval)                                   \
    {                                                     \
        const float Cc = fmaf((dval), w_, s3[kk]);        \
        acc[kk].x = fmaf(dl0, Cc, acc[kk].x);             \
        acc[kk].y = fmaf(dl1, Cc, acc[kk].y);             \
        s3[kk] = fmaf((dval), vv, s3[kk]);                \
    }
        KSTEP(0, d0) KSTEP(1, d1) KSTEP(2, d2) KSTEP(3, d3)
        KSTEP(4, d4) KSTEP(5, d5) KSTEP(6, d6) KSTEP(7, d7)
#undef KSTEP
        s2 = fmaf(dj, fmaf(di, 0.5f, s1), s2);
        s1 += di;
    }

    // write chunk lvl1-3 to LDS slot w; lvl3 layout [t1*65 + t2*8 + t3]
    {
        float* sp = lds + w * SLOT;
        if (j == 0) sp[i] = s1;
        sp[8 + i * 8 + j] = s2;
        float* s3p = sp + 72 + i * 65 + j * 8;
#pragma unroll
        for (int k = 0; k < 8; ++k) s3p[k] = s3[k];
    }
    __syncthreads();

    // ---------------- Phase B: prefix fold (lvl1-3, Chen) ----------------
    float a1 = 0.f, a2 = 0.f;
    float a3[8];
#pragma unroll
    for (int k = 0; k < 8; ++k) a3[k] = 0.f;

#define FOLD123(BP)                                                          \
    {                                                                        \
        const float4 b1lo = *reinterpret_cast<const float4*>(BP);            \
        const float4 b1hi = *reinterpret_cast<const float4*>((BP) + 4);      \
        const float4 r0 = *reinterpret_cast<const float4*>((BP) + 8 + j * 8);\
        const float4 r1 = *reinterpret_cast<const float4*>((BP) + 12 + j * 8);\
        const float b1i = (BP)[i], b1j = (BP)[j];                            \
        const float b2ij = (BP)[8 + i * 8 + j];                              \
        const float* b3p = (BP) + 72 + i * 65 + j * 8;                       \
        a3[0] = fmaf(a2, b1lo.x, fmaf(a1, r0.x, a3[0] + b3p[0]));            \
        a3[1] = fmaf(a2, b1lo.y, fmaf(a1, r0.y, a3[1] + b3p[1]));            \
        a3[2] = fmaf(a2, b1lo.z, fmaf(a1, r0.z, a3[2] + b3p[2]));            \
        a3[3] = fmaf(a2, b1lo.w, fmaf(a1, r0.w, a3[3] + b3p[3]));            \
        a3[4] = fmaf(a2, b1hi.x, fmaf(a1, r1.x, a3[4] + b3p[4]));            \
        a3[5] = fmaf(a2, b1hi.y, fmaf(a1, r1.y, a3[5] + b3p[5]));            \
        a3[6] = fmaf(a2, b1hi.z, fmaf(a1, r1.z, a3[6] + b3p[6]));            \
        a3[7] = fmaf(a2, b1hi.w, fmaf(a1, r1.w, a3[7] + b3p[7]));            \
        a2 = fmaf(a1, b1j, a2 + b2ij);                                       \
        a1 += b1i;                                                           \
    }

    {
        const float* bp = lds;
        for (int b = 0; b < w; ++b, bp += SLOT) FOLD123(bp)
    }

    // ---------------- Phase C: lvl4 contribution + LDS atomic sum --------
    {
        const float* cp = lds + w * SLOT;
        const float B1l0 = cp[lq * 2], B1l1 = cp[lq * 2 + 1];
        float* l4 = lds + L4OFF + lane * 2;
#pragma unroll
        for (int k = 0; k < 8; ++k) {
            const float B2a = cp[8 + k * 8 + lq * 2];
            const float B2b = cp[8 + k * 8 + lq * 2 + 1];
            const float B3a = cp[72 + j * 65 + k * 8 + lq * 2];
            const float B3b = cp[72 + j * 65 + k * 8 + lq * 2 + 1];
            float vx = fmaf(a3[k], B1l0, fmaf(a2, B2a, fmaf(a1, B3a, acc[k].x)));
            float vy = fmaf(a3[k], B1l1, fmaf(a2, B2b, fmaf(a1, B3b, acc[k].y)));
            atomicAdd(&l4[k * 128 + 0], vx);
            atomicAdd(&l4[k * 128 + 1], vy);
        }
    }

    // ---------------- final lvl1-3 (wave 15, lq 0) ----------------------
    if (w == 15 && lq == 0) {
        const float* bp = lds + 15 * SLOT;
        FOLD123(bp)
        float* o = out + (size_t)n * SIG;
        float4 st0, st1;
        st0.x = a3[0]; st0.y = a3[1]; st0.z = a3[2]; st0.w = a3[3];
        st1.x = a3[4]; st1.y = a3[5]; st1.z = a3[6]; st1.w = a3[7];
        *reinterpret_cast<float4*>(o + 72 + i * 64 + j * 8) = st0;
        *reinterpret_cast<float4*>(o + 72 + i * 64 + j * 8 + 4) = st1;
        o[8 + i * 8 + j] = a2;
        if (j == 0) o[i] = a1;
    }
#undef FOLD123

    __syncthreads();

    // ---------------- write lvl4 (this block's l-pair) ------------------
    if (tid < 512) {
        const int kk = tid >> 6;
        const int ln = tid & 63;
        const int tri = (ln >> 3) * 64 + (ln & 7) * 8 + kk;
        const float2 v = *reinterpret_cast<const float2*>(&lds[L4OFF + kk * 128 + ln * 2]);
        *reinterpret_cast<float2*>(out + (size_t)n * SIG + 584 + tri * 8 + lq * 2) = v;
    }
}

extern "C" void kernel_launch(void* const* d_in, const int* in_sizes, int n_in,
                              void* d_out, int out_size, void* d_ws, size_t ws_size,
                              hipStream_t stream) {
    const float* path = (const float*)d_in[0];
    float* out = (float*)d_out;
    // 64 batches x 4 l-quarters = 256 blocks (1 per CU), 1024 threads each
    sig_fused<<<256, 1024, 0, stream>>>(path, out);
}

// Round 7
// 43.267 us; speedup vs baseline: 1.0783x; 1.0783x over previous
//
#include <hip/hip_runtime.h>

// Depth-4 path signature, N=64, L=512, C=8. Output/batch:
// [sig1(8) | sig2(64) | sig3(512) | sig4(4096)] = 4680 f32.
//
// Single fused kernel, grid 256 = (batch n) x (l-quarter lq), 1024 thr = 16 waves.
//   Stage:   dx[511*8] -> LDS via 1022 parallel float4 diffs (deep MLP, ~1us).
//            (R6 lesson: 32 serial dependent global loads/wave = main stall.)
//   Phase A: wave w scans chunk w (32 segs) reading dx as 2 uniform
//            ds_read_b128/step (broadcast, conflict-free, statically
//            addressable -> compiler can prefetch). Full lvl1-3 scan +
//            lvl4 acc restricted to this block's l-pair. All state in regs.
//   Phase B: each wave folds prefix chunks 0..w-1 (lvl1-3 Chen) from LDS.
//   Phase C: chunk w's lvl4 contribution D4 = B4 + A3*B1[l] + A2*B2[kl]
//            + A1*B3[jkl] -> ds atomicAdd into 1024-float accumulator
//            (16-way inter-wave same-address contention ~0.9us, acceptable).
//   wave15/lq0: one more fold = full lvl1-3 -> out.
//   Tail: 512 threads copy summed lvl4 (this block's l-pair) to out.

static constexpr int L = 512;
static constexpr int NC = 8;
static constexpr int NSEG = L - 1;               // 511
static constexpr int SIG = 8 + 64 + 512 + 4096;  // 4680
static constexpr int DXF = NSEG * NC;            // 4088 floats
static constexpr int SLOT = 592;                 // 8 lvl1 + 64 lvl2 + 520 lvl3(stride65)
static constexpr int SLOTOFF = DXF;              // 4088
static constexpr int L4OFF = SLOTOFF + 16 * SLOT;  // 13560
static constexpr int LDSF = L4OFF + 1024;        // 14584 floats = 58336 B

__device__ __forceinline__ float sel8(float d0, float d1, float d2, float d3,
                                      float d4, float d5, float d6, float d7,
                                      bool b0, bool b1, bool b2) {
    float x0 = b0 ? d1 : d0;
    float x1 = b0 ? d3 : d2;
    float x2 = b0 ? d5 : d4;
    float x3 = b0 ? d7 : d6;
    float y0 = b1 ? x1 : x0;
    float y1 = b1 ? x3 : x2;
    return b2 ? y1 : y0;
}

__global__ __launch_bounds__(1024) void sig_fused2(const float* __restrict__ path,
                                                   float* __restrict__ out) {
    __shared__ float lds[LDSF];
    const int tid = threadIdx.x;
    const int w = tid >> 6;        // wave = chunk 0..15
    const int lane = tid & 63;
    const int i = lane >> 3;
    const int j = lane & 7;
    const int n = blockIdx.x >> 2;   // batch
    const int lq = blockIdx.x & 3;   // l-quarter: l = lq*2, lq*2+1

    // ---- stage dx into LDS (independent parallel loads) + zero l4 acc ----
    {
        const float4* pv = reinterpret_cast<const float4*>(path + (size_t)n * (L * NC));
        if (tid < DXF / 4) {  // 1022 float4 diffs
            const float4 a = pv[tid];
            const float4 b = pv[tid + 2];
            *reinterpret_cast<float4*>(&lds[tid * 4]) =
                make_float4(b.x - a.x, b.y - a.y, b.z - a.z, b.w - a.w);
        }
        lds[L4OFF + tid] = 0.f;
    }
    __syncthreads();

    // ---------------- Phase A: chunk scan (LDS-fed) ----------------
    const int seg0 = w * 32;
    const int len = min(32, NSEG - seg0);

    const bool ib0 = lane & 8, ib1 = lane & 16, ib2 = lane & 32;
    const bool jb0 = lane & 1, jb1 = lane & 2, jb2 = lane & 4;
    const bool lb0 = lq & 1, lb1 = lq & 2;

    float s1 = 0.f, s2 = 0.f;
    float s3[8];
    float2 acc[8];
#pragma unroll
    for (int k = 0; k < 8; ++k) {
        s3[k] = 0.f;
        acc[k] = make_float2(0.f, 0.f);
    }
    constexpr float c3 = 1.f / 6.f;
    constexpr float c4 = 1.f / 24.f;

    const float* dbase = lds + seg0 * 8;
#pragma unroll 4
    for (int s = 0; s < len; ++s) {
        const float4 A = *reinterpret_cast<const float4*>(dbase + s * 8);
        const float4 B = *reinterpret_cast<const float4*>(dbase + s * 8 + 4);
        const float d0 = A.x, d1 = A.y, d2 = A.z, d3 = A.w;
        const float d4 = B.x, d5 = B.y, d6 = B.z, d7 = B.w;

        const float di = sel8(d0, d1, d2, d3, d4, d5, d6, d7, ib0, ib1, ib2);
        const float dj = sel8(d0, d1, d2, d3, d4, d5, d6, d7, jb0, jb1, jb2);
        const float ea = lb0 ? d2 : d0, eb = lb0 ? d6 : d4;
        const float dl0 = lb1 ? eb : ea;
        const float ec = lb0 ? d3 : d1, ed = lb0 ? d7 : d5;
        const float dl1 = lb1 ? ed : ec;

        const float u = fmaf(s1, c3, di * c4);    // s1/6 + di/24
        float vv = fmaf(s1, dj * 0.5f, s2);       // s2 + s1*dj/2
        vv = fmaf(di * dj, c3, vv);               // + di*dj/6
        const float w_ = fmaf(s2, 0.5f, dj * u);  // s2/2 + dj*u

#define KSTEP(kk, dval)                                   \
    {                                                     \
        const float Cc = fmaf((dval), w_, s3[kk]);        \
        acc[kk].x = fmaf(dl0, Cc, acc[kk].x);             \
        acc[kk].y = fmaf(dl1, Cc, acc[kk].y);             \
        s3[kk] = fmaf((dval), vv, s3[kk]);                \
    }
        KSTEP(0, d0) KSTEP(1, d1) KSTEP(2, d2) KSTEP(3, d3)
        KSTEP(4, d4) KSTEP(5, d5) KSTEP(6, d6) KSTEP(7, d7)
#undef KSTEP
        s2 = fmaf(dj, fmaf(di, 0.5f, s1), s2);
        s1 += di;
    }

    // write chunk lvl1-3 to LDS slot w; lvl3 layout [t1*65 + t2*8 + t3]
    {
        float* sp = lds + SLOTOFF + w * SLOT;
        if (j == 0) sp[i] = s1;
        sp[8 + i * 8 + j] = s2;
        float* s3p = sp + 72 + i * 65 + j * 8;
#pragma unroll
        for (int k = 0; k < 8; ++k) s3p[k] = s3[k];
    }
    __syncthreads();

    // ---------------- Phase B: prefix fold (lvl1-3, Chen) ----------------
    float a1 = 0.f, a2 = 0.f;
    float a3[8];
#pragma unroll
    for (int k = 0; k < 8; ++k) a3[k] = 0.f;

#define FOLD123(BP)                                                          \
    {                                                                        \
        const float4 b1lo = *reinterpret_cast<const float4*>(BP);            \
        const float4 b1hi = *reinterpret_cast<const float4*>((BP) + 4);      \
        const float4 r0 = *reinterpret_cast<const float4*>((BP) + 8 + j * 8);\
        const float4 r1 = *reinterpret_cast<const float4*>((BP) + 12 + j * 8);\
        const float b1i = (BP)[i], b1j = (BP)[j];                            \
        const float b2ij = (BP)[8 + i * 8 + j];                              \
        const float* b3p = (BP) + 72 + i * 65 + j * 8;                       \
        a3[0] = fmaf(a2, b1lo.x, fmaf(a1, r0.x, a3[0] + b3p[0]));            \
        a3[1] = fmaf(a2, b1lo.y, fmaf(a1, r0.y, a3[1] + b3p[1]));            \
        a3[2] = fmaf(a2, b1lo.z, fmaf(a1, r0.z, a3[2] + b3p[2]));            \
        a3[3] = fmaf(a2, b1lo.w, fmaf(a1, r0.w, a3[3] + b3p[3]));            \
        a3[4] = fmaf(a2, b1hi.x, fmaf(a1, r1.x, a3[4] + b3p[4]));            \
        a3[5] = fmaf(a2, b1hi.y, fmaf(a1, r1.y, a3[5] + b3p[5]));            \
        a3[6] = fmaf(a2, b1hi.z, fmaf(a1, r1.z, a3[6] + b3p[6]));            \
        a3[7] = fmaf(a2, b1hi.w, fmaf(a1, r1.w, a3[7] + b3p[7]));            \
        a2 = fmaf(a1, b1j, a2 + b2ij);                                       \
        a1 += b1i;                                                           \
    }

    {
        const float* bp = lds + SLOTOFF;
        for (int b = 0; b < w; ++b, bp += SLOT) FOLD123(bp)
    }

    // ---------------- Phase C: lvl4 contribution + LDS atomic sum --------
    {
        const float* cp = lds + SLOTOFF + w * SLOT;
        const float B1l0 = cp[lq * 2], B1l1 = cp[lq * 2 + 1];
        float* l4 = lds + L4OFF + lane * 2;
#pragma unroll
        for (int k = 0; k < 8; ++k) {
            const float B2a = cp[8 + k * 8 + lq * 2];
            const float B2b = cp[8 + k * 8 + lq * 2 + 1];
            const float B3a = cp[72 + j * 65 + k * 8 + lq * 2];
            const float B3b = cp[72 + j * 65 + k * 8 + lq * 2 + 1];
            float vx = fmaf(a3[k], B1l0, fmaf(a2, B2a, fmaf(a1, B3a, acc[k].x)));
            float vy = fmaf(a3[k], B1l1, fmaf(a2, B2b, fmaf(a1, B3b, acc[k].y)));
            atomicAdd(&l4[k * 128 + 0], vx);
            atomicAdd(&l4[k * 128 + 1], vy);
        }
    }

    // ---------------- final lvl1-3 (wave 15, lq 0) ----------------------
    if (w == 15 && lq == 0) {
        const float* bp = lds + SLOTOFF + 15 * SLOT;
        FOLD123(bp)
        float* o = out + (size_t)n * SIG;
        float4 st0, st1;
        st0.x = a3[0]; st0.y = a3[1]; st0.z = a3[2]; st0.w = a3[3];
        st1.x = a3[4]; st1.y = a3[5]; st1.z = a3[6]; st1.w = a3[7];
        *reinterpret_cast<float4*>(o + 72 + i * 64 + j * 8) = st0;
        *reinterpret_cast<float4*>(o + 72 + i * 64 + j * 8 + 4) = st1;
        o[8 + i * 8 + j] = a2;
        if (j == 0) o[i] = a1;
    }
#undef FOLD123

    __syncthreads();

    // ---------------- write lvl4 (this block's l-pair) ------------------
    if (tid < 512) {
        const int kk = tid >> 6;
        const int ln = tid & 63;
        const int tri = (ln >> 3) * 64 + (ln & 7) * 8 + kk;
        const float2 v = *reinterpret_cast<const float2*>(&lds[L4OFF + kk * 128 + ln * 2]);
        *reinterpret_cast<float2*>(out + (size_t)n * SIG + 584 + tri * 8 + lq * 2) = v;
    }
}

extern "C" void kernel_launch(void* const* d_in, const int* in_sizes, int n_in,
                              void* d_out, int out_size, void* d_ws, size_t ws_size,
                              hipStream_t stream) {
    const float* path = (const float*)d_in[0];
    float* out = (float*)d_out;
    // 64 batches x 4 l-quarters = 256 blocks (1 per CU), 1024 threads each
    sig_fused2<<<256, 1024, 0, stream>>>(path, out);
}